// Round 3
// baseline (99.352 us; speedup 1.0000x reference)
//
#include <hip/hip_runtime.h>

// SiamFC cross-correlation: out[n,0,oh,ow] = sum_{c,i,j} x[n,c,oh+i,ow+j] * z[n,c,i,j]
// n=256, c=256, z=6x6, x=26x26, out=21x21.
//
// Block = 256 threads: 176 compute lanes = 16 channels x 11 row-tiles (TH=2, full
// 21-wide). LDS x rows padded 26->28 (16B-aligned b128), channel stride 732
// (mod 32 = 28 -> odd bank-group rotation per channel). Each x row is read once
// per thread (7 b128) and feeds 252 FMAs (z rows xr, xr-1 streamed in regs).

#define C_ALL 256
#define HZ 6
#define WZ 6
#define HX 26
#define WX 26
#define OH 21
#define OW 21
#define PADW 28
#define CHS 732                    // LDS channel stride (26*28=728 + 4)
#define ZSTR 38                    // LDS z channel stride (36 + 2) -> spread broadcasts
#define CCON 16                    // channels staged per round
#define ROUNDS 2                   // 32 channels per block -> 8 splits/sample
#define NTHREADS 256
#define NTILES 11                  // row-tiles of 2 output rows
#define ACTIVE_T (CCON * NTILES)   // 176 compute lanes
#define RED_STRIDE 456

__global__ __launch_bounds__(NTHREADS, 3)
void siamfc_xcorr(const float* __restrict__ z, const float* __restrict__ x,
                  float* __restrict__ out) {
    __shared__ float xs[CCON * CHS + 32];   // 46.9 KB (+32 guard for t=10 row-26 overread)
    __shared__ float zs[CCON * ZSTR];

    const int tid = threadIdx.x;
    const int bid = blockIdx.x;
    const int n     = bid >> 3;
    const int split = bid & 7;
    const int cbase0 = split * (CCON * ROUNDS);

    const int cc = tid / NTILES;        // 0..15 for tid<176
    const int t  = tid - cc * NTILES;   // 0..10
    const bool active = (tid < ACTIVE_T);
    const int r0 = 2 * t;               // output rows r0, r0+1 (r0+1 discarded for t=10)

    float acc0[OW], acc1[OW];
    #pragma unroll
    for (int o = 0; o < OW; ++o) { acc0[o] = 0.f; acc1[o] = 0.f; }

    const float2* xg = (const float2*)(x + (size_t)n * C_ALL * (HX * WX));
    const float2* zg = (const float2*)(z + (size_t)n * C_ALL * (HZ * WZ));

    for (int round = 0; round < ROUNDS; ++round) {
        const int cbase = cbase0 + round * CCON;
        __syncthreads();
        // ---- stage x: 16 ch x 338 float2 (contiguous global), pad rows 26->28
        {
            const float2* src = xg + (size_t)cbase * (HX * WX / 2);
            for (int u = tid; u < CCON * HX * (WX / 2); u += NTHREADS) {
                float2 v = src[u];
                int ch  = u / (HX * WX / 2);          // /338
                int rem = u - ch * (HX * WX / 2);
                int row = rem / (WX / 2);             // /13
                int seg = rem - row * (WX / 2);
                *(float2*)&xs[ch * CHS + row * PADW + 2 * seg] = v;
            }
            // ---- stage z: 16 ch x 18 float2
            const float2* zsrc = zg + (size_t)cbase * (HZ * WZ / 2);
            for (int u = tid; u < CCON * (HZ * WZ / 2); u += NTHREADS) {
                float2 v = zsrc[u];
                int ch  = u / (HZ * WZ / 2);          // /18
                int rem = u - ch * (HZ * WZ / 2);
                *(float2*)&zs[ch * ZSTR + 2 * rem] = v;
            }
        }
        __syncthreads();

        if (active) {
            const float* xc = xs + cc * CHS;
            const float* zc = zs + cc * ZSTR;
            float zcur[WZ], zprev[WZ];
            #pragma unroll
            for (int xr = 0; xr < 7; ++xr) {          // x rows r0..r0+6, each read ONCE
                float xrow[PADW];
                const float4* rp = (const float4*)(xc + (r0 + xr) * PADW);
                #pragma unroll
                for (int k = 0; k < 7; ++k) {
                    float4 f = rp[k];
                    xrow[4*k+0] = f.x; xrow[4*k+1] = f.y;
                    xrow[4*k+2] = f.z; xrow[4*k+3] = f.w;
                }
                if (xr > 0) {
                    #pragma unroll
                    for (int j = 0; j < WZ; ++j) zprev[j] = zcur[j];
                }
                if (xr < HZ) {   // load z row xr (3 b64 broadcast reads)
                    const float2* zr = (const float2*)(zc + xr * WZ);
                    float2 a = zr[0], b = zr[1], c = zr[2];
                    zcur[0]=a.x; zcur[1]=a.y; zcur[2]=b.x;
                    zcur[3]=b.y; zcur[4]=c.x; zcur[5]=c.y;
                    #pragma unroll
                    for (int j = 0; j < WZ; ++j)
                        #pragma unroll
                        for (int o = 0; o < OW; ++o)
                            acc0[o] = fmaf(zcur[j], xrow[o + j], acc0[o]);
                }
                if (xr > 0) {    // contributes to output row r0+1 via z row xr-1
                    #pragma unroll
                    for (int j = 0; j < WZ; ++j)
                        #pragma unroll
                        for (int o = 0; o < OW; ++o)
                            acc1[o] = fmaf(zprev[j], xrow[o + j], acc1[o]);
                }
            }
        }
    }

    // ---- reduce across the 16 cc groups (reuse xs), then 8-way global atomic
    __syncthreads();
    if (active) {
        float* red = xs + cc * RED_STRIDE;
        #pragma unroll
        for (int o = 0; o < OW; ++o) red[r0 * OW + o] = acc0[o];
        if (t < 10) {
            #pragma unroll
            for (int o = 0; o < OW; ++o) red[(r0 + 1) * OW + o] = acc1[o];
        }
    }
    __syncthreads();
    float* og = out + (size_t)n * (OH * OW);
    for (int o = tid; o < OH * OW; o += NTHREADS) {
        float s = 0.f;
        #pragma unroll
        for (int c2 = 0; c2 < CCON; ++c2) s += xs[c2 * RED_STRIDE + o];
        atomicAdd(&og[o], s);
    }
}

extern "C" void kernel_launch(void* const* d_in, const int* in_sizes, int n_in,
                              void* d_out, int out_size, void* d_ws, size_t ws_size,
                              hipStream_t stream) {
    const float* z = (const float*)d_in[0];
    const float* x = (const float*)d_in[1];
    float* out = (float*)d_out;
    hipMemsetAsync(d_out, 0, (size_t)out_size * sizeof(float), stream);
    siamfc_xcorr<<<dim3(256 * 8), dim3(NTHREADS), 0, stream>>>(z, x, out);
}

// Round 4
// 93.403 us; speedup vs baseline: 1.0637x; 1.0637x over previous
//
#include <hip/hip_runtime.h>

// SiamFC cross-correlation: out[n,0,oh,ow] = sum_{c,i,j} x[n,c,oh+i,ow+j] * z[n,c,i,j]
// n=256, c=256, z=6x6, x=26x26, out=21x21.
//
// Latency-bound fix: maximize resident waves. Block = 384 threads, 336 active =
// 8 channels x 2 z-row-halves x 21 output rows. Each thread: full 21-col row,
// z rows 3h..3h+2 only (3 x-rows, 7 b128 each, 378 FMAs/channel). LDS 24.8 KB
// -> 4-5 blocks/CU (24-30 waves). CHS=732 floats: 183 = 7 mod 8 -> odd bank-phase
// rotation per channel; phase = -(cc + r + 3h) mod 8 spreads 64 lanes uniformly.

#define C_ALL 256
#define HZ 6
#define WZ 6
#define HX 26
#define WX 26
#define OH 21
#define OW 21
#define PADW 28
#define CHS 732                    // LDS x channel stride (26*28=728 + 4)
#define ZSTR 38
#define CCON 8                     // channels staged per round
#define ROUNDS 4                   // 32 channels per block -> 8 splits/sample
#define NTHREADS 384
#define ACTIVE_T (CCON * 2 * OH)   // 336
#define RED_STRIDE 456

__global__ __launch_bounds__(NTHREADS, 7)
void siamfc_xcorr(const float* __restrict__ z, const float* __restrict__ x,
                  float* __restrict__ out) {
    __shared__ __align__(16) float xs[CCON * CHS];   // 5856 floats = 23424 B (reused for reduction)
    __shared__ float zs[CCON * ZSTR];                // 304 floats

    const int tid = threadIdx.x;
    const int bid = blockIdx.x;
    const int n     = bid >> 3;
    const int split = bid & 7;
    const int cbase0 = split * (CCON * ROUNDS);

    const int cc  = tid / 42;            // 0..7 for tid<336
    const int rem = tid - cc * 42;
    const int h   = rem / 21;            // z-row half: z rows 3h..3h+2
    const int r   = rem - h * 21;        // output row 0..20
    const bool active = (tid < ACTIVE_T);

    float acc[OW];
    #pragma unroll
    for (int o = 0; o < OW; ++o) acc[o] = 0.f;

    const float2* xg = (const float2*)(x + (size_t)n * C_ALL * (HX * WX));
    const float2* zg = (const float2*)(z + (size_t)n * C_ALL * (HZ * WZ));

    #pragma unroll 1
    for (int round = 0; round < ROUNDS; ++round) {
        const int cbase = cbase0 + round * CCON;
        __syncthreads();
        // ---- stage x: 8 ch x 338 float2 (contiguous global), pad rows 26->28
        {
            const float2* src = xg + (size_t)cbase * (HX * WX / 2);
            for (int u = tid; u < CCON * HX * (WX / 2); u += NTHREADS) {
                float2 v = src[u];
                int ch  = u / 338;
                int rm  = u - ch * 338;
                int row = rm / 13;
                int seg = rm - row * 13;
                *(float2*)&xs[ch * CHS + row * PADW + 2 * seg] = v;
            }
            // ---- stage z: 8 ch x 18 float2
            const float2* zsrc = zg + (size_t)cbase * (HZ * WZ / 2);
            for (int u = tid; u < CCON * (HZ * WZ / 2); u += NTHREADS) {
                float2 v = zsrc[u];
                int ch = u / 18;
                int rm = u - ch * 18;
                *(float2*)&zs[ch * ZSTR + 2 * rm] = v;
            }
        }
        __syncthreads();

        if (active) {
            const float* xc = xs + cc * CHS;
            const float* zc = zs + cc * ZSTR + h * (3 * WZ);
            #pragma unroll
            for (int xr = 0; xr < 3; ++xr) {
                const int row = r + 3 * h + xr;      // <= 20+3+2 = 25, in-bounds
                const float4* rp = (const float4*)(xc + row * PADW);
                float xrow[PADW];
                #pragma unroll
                for (int k = 0; k < 7; ++k) {
                    float4 f = rp[k];
                    xrow[4*k+0] = f.x; xrow[4*k+1] = f.y;
                    xrow[4*k+2] = f.z; xrow[4*k+3] = f.w;
                }
                const float2* zr = (const float2*)(zc + xr * WZ);
                float2 a = zr[0], b = zr[1], c = zr[2];
                float zv[WZ] = {a.x, a.y, b.x, b.y, c.x, c.y};
                #pragma unroll
                for (int j = 0; j < WZ; ++j)
                    #pragma unroll
                    for (int o = 0; o < OW; ++o)
                        acc[o] = fmaf(zv[j], xrow[o + j], acc[o]);
            }
        }
    }

    // ---- combine h-halves in LDS, then cross-cc sum + 8-way global atomic
    __syncthreads();
    if (active && h == 0) {
        float* red = xs + cc * RED_STRIDE + r * OW;
        #pragma unroll
        for (int o = 0; o < OW; ++o) red[o] = acc[o];
    }
    __syncthreads();
    if (active && h == 1) {
        float* red = xs + cc * RED_STRIDE + r * OW;
        #pragma unroll
        for (int o = 0; o < OW; ++o) red[o] += acc[o];
    }
    __syncthreads();
    float* og = out + (size_t)n * (OH * OW);
    for (int o = tid; o < OH * OW; o += NTHREADS) {
        float s = 0.f;
        #pragma unroll
        for (int c2 = 0; c2 < CCON; ++c2) s += xs[c2 * RED_STRIDE + o];
        atomicAdd(&og[o], s);
    }
}

extern "C" void kernel_launch(void* const* d_in, const int* in_sizes, int n_in,
                              void* d_out, int out_size, void* d_ws, size_t ws_size,
                              hipStream_t stream) {
    const float* z = (const float*)d_in[0];
    const float* x = (const float*)d_in[1];
    float* out = (float*)d_out;
    hipMemsetAsync(d_out, 0, (size_t)out_size * sizeof(float), stream);
    siamfc_xcorr<<<dim3(256 * 8), dim3(NTHREADS), 0, stream>>>(z, x, out);
}